// Round 4
// baseline (35.698 us; speedup 1.0000x reference)
//
#include <hip/hip_runtime.h>

// out[b][l] = x[b][perm[b][l]]  — per-row pseudo-random interleave.
// B=1024 rows, L=16384 elements/row (fp32). Row = 64 KiB -> stage in LDS,
// gather from LDS, all global traffic fully coalesced via float4/int4.
//
// r1: 1024-thread blocks -> 32 waves/CU at the pinned 64 KiB LDS/block.
// r2/r3: nontemporal output stores (via ext_vector float4 — the builtin
//     rejects HIP_vector_type). Working set (x 64MiB + perm 64MiB +
//     out 64MiB = 192MiB) fits in the 256MiB L3, but write-allocating
//     stores evicted the inputs each call (FETCH_SIZE stuck at 64MiB).
//     out is write-only -> NT store keeps x+perm L3-resident, HBM traffic
//     drops toward the pure 64MiB write stream.

constexpr int L = 16384;
constexpr int BLOCK = 1024;
constexpr int VEC = L / 4 / BLOCK;  // 4 float4 / int4 per thread

typedef float f32x4 __attribute__((ext_vector_type(4)));

__global__ __launch_bounds__(BLOCK) void interleave_kernel(
    const float* __restrict__ x,
    const int* __restrict__ perm,
    float* __restrict__ out) {
  extern __shared__ float row[];  // 16384 floats = 64 KiB

  const long long base = (long long)blockIdx.x * L;
  const float4* __restrict__ x4 = reinterpret_cast<const float4*>(x + base);
  const int4* __restrict__ p4 = reinterpret_cast<const int4*>(perm + base);
  float4* __restrict__ row4 = reinterpret_cast<float4*>(row);
  f32x4* __restrict__ o4 = reinterpret_cast<f32x4*>(out + base);

  // Issue perm loads first so they are in flight across the staging phase.
  int4 p[VEC];
#pragma unroll
  for (int i = 0; i < VEC; ++i) {
    p[i] = p4[threadIdx.x + i * BLOCK];
  }

  // Stage the row into LDS, coalesced 16 B/lane.
#pragma unroll
  for (int i = 0; i < VEC; ++i) {
    const int idx = threadIdx.x + i * BLOCK;
    row4[idx] = x4[idx];
  }
  __syncthreads();

#pragma unroll
  for (int i = 0; i < VEC; ++i) {
    f32x4 v;
    v.x = row[p[i].x];
    v.y = row[p[i].y];
    v.z = row[p[i].z];
    v.w = row[p[i].w];
    __builtin_nontemporal_store(v, &o4[threadIdx.x + i * BLOCK]);
  }
}

extern "C" void kernel_launch(void* const* d_in, const int* in_sizes, int n_in,
                              void* d_out, int out_size, void* d_ws, size_t ws_size,
                              hipStream_t stream) {
  const float* x = (const float*)d_in[0];
  const int* perm = (const int*)d_in[1];
  float* out = (float*)d_out;

  const int B = out_size / L;  // 1024
  interleave_kernel<<<B, BLOCK, L * sizeof(float), stream>>>(x, perm, out);
}

// Round 5
// 35.072 us; speedup vs baseline: 1.0179x; 1.0179x over previous
//
#include <hip/hip_runtime.h>

// out[b][l] = x[b][perm[b][l]]  — per-row pseudo-random interleave.
// B=1024 rows, L=16384 elements/row (fp32). Row = 64 KiB -> stage in LDS,
// gather from LDS, all global traffic fully coalesced via float4/int4.
//
// r1: 1024-thread blocks -> 32 waves/CU at the pinned 64 KiB LDS/block.
// r4 post-mortem: NT store was -4% and FETCH_SIZE unchanged -> reverted.
// r5: x staged via __builtin_amdgcn_global_load_lds (16B DMA, no VGPR
//     round-trip). LDS layout is linear in lane order (wave-uniform base +
//     lane*16), which matches our i*BLOCK + tid indexing exactly.

constexpr int L = 16384;
constexpr int BLOCK = 1024;
constexpr int VEC = L / 4 / BLOCK;  // 4 float4 / int4 per thread

__global__ __launch_bounds__(BLOCK) void interleave_kernel(
    const float* __restrict__ x,
    const int* __restrict__ perm,
    float* __restrict__ out) {
  extern __shared__ float row[];  // 16384 floats = 64 KiB

  const long long base = (long long)blockIdx.x * L;
  const float4* __restrict__ x4 = reinterpret_cast<const float4*>(x + base);
  const int4* __restrict__ p4 = reinterpret_cast<const int4*>(perm + base);
  float4* __restrict__ o4 = reinterpret_cast<float4*>(out + base);

  const int wave = threadIdx.x >> 6;  // 16 waves/block

  // Async DMA: x row -> LDS, 16 B/lane, 1 KiB per wave-issue.
  // HW writes lds_base + lane*16; lds_base is wave-uniform.
#pragma unroll
  for (int i = 0; i < VEC; ++i) {
    const int idx = threadIdx.x + i * BLOCK;           // per-lane global index
    const float4* gsrc = x4 + idx;
    char* ldst = (char*)row + (size_t)(i * BLOCK + wave * 64) * 16;
    __builtin_amdgcn_global_load_lds(
        (const __attribute__((address_space(1))) void*)gsrc,
        (__attribute__((address_space(3))) void*)ldst, 16, 0, 0);
  }

  // perm loads issue in parallel with the DMA.
  int4 p[VEC];
#pragma unroll
  for (int i = 0; i < VEC; ++i) {
    p[i] = p4[threadIdx.x + i * BLOCK];
  }

  __syncthreads();  // compiler emits s_waitcnt vmcnt(0) before s_barrier

#pragma unroll
  for (int i = 0; i < VEC; ++i) {
    float4 v;
    v.x = row[p[i].x];
    v.y = row[p[i].y];
    v.z = row[p[i].z];
    v.w = row[p[i].w];
    o4[threadIdx.x + i * BLOCK] = v;
  }
}

extern "C" void kernel_launch(void* const* d_in, const int* in_sizes, int n_in,
                              void* d_out, int out_size, void* d_ws, size_t ws_size,
                              hipStream_t stream) {
  const float* x = (const float*)d_in[0];
  const int* perm = (const int*)d_in[1];
  float* out = (float*)d_out;

  const int B = out_size / L;  // 1024
  interleave_kernel<<<B, BLOCK, L * sizeof(float), stream>>>(x, perm, out);
}